// Round 8
// baseline (224.341 us; speedup 1.0000x reference)
//
#include <hip/hip_runtime.h>
#include <math.h>

#define NTP 256     // prep kernel block
#define NT 64       // main kernel: ONE wave per block = one batch element
#define NS 4096     // 2^12 amplitudes

typedef float f32x2 __attribute__((ext_vector_type(2)));

// CNOT ring: gates CNOT(i,(i+1)%12), wire j <-> bit (11-j).
// forward basis permutation pi(k), GF(2)-linear:
constexpr int ring_pi_c(int k) {
    int u = k ^ (k >> 1);
    u ^= u >> 2; u ^= u >> 4; u ^= u >> 8;
    int w0 = ((u >> 11) ^ u) & 1;
    return (u & 0x7FF) | (w0 << 11);
}
// storage swizzle: low nibble ^= g(k[9:6]); g = (J^I)U^-1 construction makes
// A-pass, B-pass AND ring-scatter all bank-conflict-free (verified per-quarter bijective).
constexpr int gfun(int n) {
    int n0 = n & 1, n1 = (n >> 1) & 1, n2 = (n >> 2) & 1, n3 = (n >> 3) & 1;
    return (n1) | ((n0 ^ n1 ^ n2) << 1) | ((n0 ^ n2 ^ n3) << 2) | ((n0 ^ n3) << 3);
}
constexpr int sigf(int k) { return k ^ gfun((k >> 6) & 15); }

// Fused gate G = [[A-iB, -C+iD],[C+iD, A+iB]] applied to (a0,a1), packed fp32.
__device__ __forceinline__ void app1p(f32x2 ab, f32x2 cd, f32x2& a0, f32x2& a1) {
    f32x2 n0, n1;
    asm("v_pk_mul_f32 %0, %2, %4 op_sel:[0,0] op_sel_hi:[1,0]\n\t"
        "v_pk_fma_f32 %0, %2, %4, %0 op_sel:[1,1,0] op_sel_hi:[0,1,1] neg_hi:[0,1,0]\n\t"
        "v_pk_fma_f32 %0, %3, %5, %0 op_sel:[0,0,0] op_sel_hi:[1,0,1] neg_lo:[0,1,0] neg_hi:[0,1,0]\n\t"
        "v_pk_fma_f32 %0, %3, %5, %0 op_sel:[1,1,0] op_sel_hi:[0,1,1] neg_lo:[0,1,0]\n\t"
        "v_pk_mul_f32 %1, %3, %4 op_sel:[0,0] op_sel_hi:[1,0]\n\t"
        "v_pk_fma_f32 %1, %3, %4, %1 op_sel:[1,1,0] op_sel_hi:[0,1,1] neg_lo:[0,1,0]\n\t"
        "v_pk_fma_f32 %1, %2, %5, %1 op_sel:[0,0,0] op_sel_hi:[1,0,1]\n\t"
        "v_pk_fma_f32 %1, %2, %5, %1 op_sel:[1,1,0] op_sel_hi:[0,1,1] neg_lo:[0,1,0]"
        : "=&v"(n0), "=&v"(n1)
        : "v"(a0), "v"(a1), "v"(ab), "v"(cd));
    a0 = n0; a1 = n1;
}

template<int P>
__device__ __forceinline__ void gate_on_bit6(f32x2 a[64], f32x2 ab, f32x2 cd) {
    #pragma unroll
    for (int r = 0; r < 64; ++r)
        if (!(r & (1 << P)))
            app1p(ab, cd, a[r], a[r | (1 << P)]);
}

// load fused gate; for lay==3 fold in RX(x[b*24+12+w]) (ABCD closed form)
__device__ __forceinline__ void load_gate(const float4* __restrict__ Uw,
                                          const float2* __restrict__ cs12,
                                          int lay, int w, bool fold,
                                          f32x2& ab, f32x2& cd) {
    float4 g = Uw[lay * 12 + w];
    float A = g.x, B = g.y, C = g.z, D = g.w;
    if (fold) {
        float2 sc = cs12[w];
        float c = sc.x, s = sc.y;
        float A2 = A*c + D*s, B2 = B*c - C*s, C2 = C*c + B*s, D2 = D*c - A*s;
        A = A2; B = B2; C = C2; D = D2;
    }
    ab = f32x2{A, B}; cd = f32x2{C, D};
}

// ---- prep kernel: cos/sin of all encode half-angles + batch-independent fused U
__global__ void prep_kernel(const float* __restrict__ x,     // (B,24)
                            const float* __restrict__ wts,   // (6,3,12)
                            float4* __restrict__ Uw,         // 72
                            float2* __restrict__ cs,         // B*24
                            int total)                       // B*24
{
    int idx = blockIdx.x * blockDim.x + threadIdx.x;
    if (idx < total) {
        float th = 0.5f * x[idx];
        float s, c; sincosf(th, &s, &c);
        cs[idx] = make_float2(c, s);
    }
    if (idx < 72) {
        int ab = idx / 12, w = idx % 12;
        float a  = 0.5f * wts[(ab * 3 + 0) * 12 + w];
        float bb = 0.5f * wts[(ab * 3 + 1) * 12 + w];
        float g  = 0.5f * wts[(ab * 3 + 2) * 12 + w];
        float sa, ca, sb, cb, sg, cg;
        sincosf(a,  &sa, &ca);
        sincosf(bb, &sb, &cb);
        sincosf(g,  &sg, &cg);
        float A = cb * (ca * cg - sa * sg);
        float B = sb * (ca * cg + sa * sg);
        float C = cb * (sa * cg + ca * sg);
        float D = sb * (sa * cg - ca * sg);
        Uw[idx] = make_float4(A, B, C, D);
    }
}

// One wave = one batch element. State A: lane=k[5:0], regs=k[11:6] (wires 0..5 reg-local).
// State B: lane=k[11:6], regs=k[5:0] (wires 6..11 reg-local). LDS only for A<->B transposes.
__global__ __launch_bounds__(NT, 1)   // allow full VGPR budget; LDS 32KB -> 5 blocks/CU
void tqhea_kernel(const float4* __restrict__ Uw,   // 72 fused gates (ABCD)
                  const float2* __restrict__ cs,   // (B,24) encode (cos,sin)
                  float* __restrict__ out)         // (B,1)
{
    __shared__ f32x2 psi[NS];        // 32 KB, sigf-swizzled storage

    const int b  = blockIdx.x;
    const int ln = threadIdx.x;      // lane 0..63

    const float2* csb  = cs + b * 24;
    const float2* cs12 = csb + 12;

    f32x2 a[64];                     // the whole statevector slice, in registers

    // ---- init: |0..0> + first RX layer = product state, directly in state-A registers
    {
        float2 rc[12];
        #pragma unroll
        for (int i = 0; i < 12; ++i) rc[i] = csb[i];
        float mlan = 1.f;
        #pragma unroll
        for (int bit = 0; bit < 6; ++bit)          // lane bit t <-> k bit t <-> wire 11-t
            mlan *= ((ln >> bit) & 1) ? rc[11 - bit].y : rc[11 - bit].x;
        int q = __popc(ln) & 3;                    // (-i)^popc(lane part)
        float pre = (q == 0) ? mlan : (q == 2) ? -mlan : 0.f;
        float pim = (q == 1) ? -mlan : (q == 3) ? mlan : 0.f;
        float mA[8], mB[8];  // reg bits 5..3 -> wires 0,1,2 ; bits 2..0 -> wires 3,4,5
        #pragma unroll
        for (int i = 0; i < 8; ++i) {
            mA[i] = (((i>>2)&1)?rc[0].y:rc[0].x) * (((i>>1)&1)?rc[1].y:rc[1].x) * ((i&1)?rc[2].y:rc[2].x);
            mB[i] = (((i>>2)&1)?rc[3].y:rc[3].x) * (((i>>1)&1)?rc[4].y:rc[4].x) * ((i&1)?rc[5].y:rc[5].x);
        }
        #pragma unroll
        for (int r = 0; r < 64; ++r) {
            float m = mA[r >> 3] * mB[r & 7];
            const int rot = __popc(r) & 3;         // static after unroll
            float vx, vy;
            if (rot == 0)      { vx =  pre * m; vy =  pim * m; }
            else if (rot == 1) { vx =  pim * m; vy = -pre * m; }
            else if (rot == 2) { vx = -pre * m; vy = -pim * m; }
            else               { vx = -pim * m; vy =  pre * m; }
            a[r] = f32x2{vx, vy};
        }
    }

    const int gl    = gfun(ln & 15);
    const int baseB = (ln << 6) | gl;              // B access: idx = (baseB ^ (r&15)) | (r&48)
    const int baseR = sigf(ring_pi_c(ln << 6));    // ring scatter: idx = baseR ^ sigf(pi(r))
    const int Pl    = ring_pi_c(ln << 6);          // reduction diag

    float acc = 0.f;

    #pragma unroll 1
    for (int lay = 0; lay < 6; ++lay) {
        const bool fold = (lay == 3);              // mid-circuit RX layer folded in
        f32x2 gab, gcd;

        // ---- state A: wires 0..5 on reg bits 5..0 (pure VALU)
        load_gate(Uw, cs12, lay, 0, fold, gab, gcd); gate_on_bit6<5>(a, gab, gcd);
        load_gate(Uw, cs12, lay, 1, fold, gab, gcd); gate_on_bit6<4>(a, gab, gcd);
        load_gate(Uw, cs12, lay, 2, fold, gab, gcd); gate_on_bit6<3>(a, gab, gcd);
        load_gate(Uw, cs12, lay, 3, fold, gab, gcd); gate_on_bit6<2>(a, gab, gcd);
        load_gate(Uw, cs12, lay, 4, fold, gab, gcd); gate_on_bit6<1>(a, gab, gcd);
        load_gate(Uw, cs12, lay, 5, fold, gab, gcd); gate_on_bit6<0>(a, gab, gcd);

        // ---- T1: A -> B transpose through LDS (conflict-free by sigf)
        #pragma unroll
        for (int r = 0; r < 64; ++r)
            psi[(r << 6) | (ln ^ gfun(r & 15))] = a[r];
        __syncthreads();                           // 1-wave barrier: just a waitcnt, ~free
        #pragma unroll
        for (int r = 0; r < 64; ++r)
            a[r] = psi[(baseB ^ (r & 15)) | (r & 48)];

        // ---- state B: wires 6..11 on reg bits 5..0
        load_gate(Uw, cs12, lay, 6,  fold, gab, gcd); gate_on_bit6<5>(a, gab, gcd);
        load_gate(Uw, cs12, lay, 7,  fold, gab, gcd); gate_on_bit6<4>(a, gab, gcd);
        load_gate(Uw, cs12, lay, 8,  fold, gab, gcd); gate_on_bit6<3>(a, gab, gcd);
        load_gate(Uw, cs12, lay, 9,  fold, gab, gcd); gate_on_bit6<2>(a, gab, gcd);
        load_gate(Uw, cs12, lay, 10, fold, gab, gcd); gate_on_bit6<1>(a, gab, gcd);
        load_gate(Uw, cs12, lay, 11, fold, gab, gcd); gate_on_bit6<0>(a, gab, gcd);

        if (lay < 5) {
            // ---- T2: ring-folded B -> A transpose; sigf(pi(.)) linear -> addr = baseR ^ const
            #pragma unroll
            for (int r = 0; r < 64; ++r)
                psi[baseR ^ sigf(ring_pi_c(r))] = a[r];
            __syncthreads();
            #pragma unroll
            for (int r = 0; r < 64; ++r)
                a[r] = psi[(r << 6) | (ln ^ gfun(r & 15))];
        } else {
            // ---- <H>: final ring via pi; diag = 12 - 2*popc(pi(k)), k=(ln<<6)|r
            #pragma unroll
            for (int r = 0; r < 64; ++r) {
                float d = 12.0f - 2.0f * (float)__popc(Pl ^ ring_pi_c(r));
                acc += (a[r].x * a[r].x + a[r].y * a[r].y) * d;
            }
        }
    }

    // ---- full-wave reduce, lane 0 writes
    #pragma unroll
    for (int off = 32; off > 0; off >>= 1)
        acc += __shfl_down(acc, off);
    if (ln == 0) out[b] = acc;
}

extern "C" void kernel_launch(void* const* d_in, const int* in_sizes, int n_in,
                              void* d_out, int out_size, void* d_ws, size_t ws_size,
                              hipStream_t stream) {
    const float* x   = (const float*)d_in[0];   // (B, 24) float32
    const float* wts = (const float*)d_in[1];   // (6, 3, 12) float32
    float* out = (float*)d_out;                 // (B, 1) float32
    int B = in_sizes[0] / 24;

    float4* Uw = (float4*)d_ws;                       // 72 * 16 B
    float2* cs = (float2*)((char*)d_ws + 1152);       // B*24 * 8 B
    int total = B * 24;

    prep_kernel<<<dim3((total + NTP - 1) / NTP), dim3(NTP), 0, stream>>>(x, wts, Uw, cs, total);
    tqhea_kernel<<<dim3(B), dim3(NT), 0, stream>>>(Uw, cs, out);
}